// Round 1
// baseline (366.407 us; speedup 1.0000x reference)
//
#include <hip/hip_runtime.h>
#include <math.h>

constexpr int B = 4, H = 16, S = 2048, D = 64;
constexpr int BH = B * H;
constexpr int QTILE = 64;       // q rows per block
constexpr int KVB = 64;         // kv rows per iteration
constexpr int NQT = S / QTILE;  // 32
constexpr float INV_SCALE = 0.125f;  // 1/sqrt(64)

typedef float f32x4 __attribute__((ext_vector_type(4)));
typedef _Float16 f16x8 __attribute__((ext_vector_type(8)));
typedef _Float16 f16x4 __attribute__((ext_vector_type(4)));

#define MFMA(a, b, c) __builtin_amdgcn_mfma_f32_16x16x32_f16((a), (b), (c), 0, 0, 0)

// Flash attention fwd, causal. 4 waves/block, each wave owns 16 q rows.
// A-frag (16x32 f16): lane holds row (lane&15), k = (lane>>4)*8 + j.
// B-frag (32x16 f16): lane holds col (lane&15), k = (lane>>4)*8 + j.
// C/D  (16x16 f32x4): col = lane&15, row = (lane>>4)*4 + reg   [m89/m91]
__global__ __launch_bounds__(256, 4)
void attn_fwd(const float* __restrict__ qp, const float* __restrict__ kp,
              const float* __restrict__ vp, float* __restrict__ op) {
  const int qt = (int)gridDim.x - 1 - (int)blockIdx.x;  // heavy tiles first
  const int bh = blockIdx.y;
  const int tid = threadIdx.x;
  const int wid = tid >> 6;
  const int lane = tid & 63;
  const int lq = lane & 15;
  const int lg = lane >> 4;

  // 72-halfs row stride (144 B): rows step 4 banks -> only free 2-way conflicts
  __shared__ __align__(16) _Float16 Kl[KVB][72];
  __shared__ __align__(16) _Float16 Vt[D][72];       // Vt[d][k]
  __shared__ __align__(16) _Float16 Pl[4][16][72];   // per-wave P tile

  const size_t base = (size_t)bh * S * D;

  // ---- Q fragments (pre-scaled by 1/sqrt(D))
  f16x8 aq[2];
  {
    const float* qg = qp + base + (size_t)(qt * QTILE + wid * 16 + lq) * D;
    for (int kk = 0; kk < 2; ++kk) {
      f32x4 q0 = *(const f32x4*)(qg + kk * 32 + lg * 8);
      f32x4 q1 = *(const f32x4*)(qg + kk * 32 + lg * 8 + 4);
      for (int j = 0; j < 4; ++j) aq[kk][j] = (_Float16)(q0[j] * INV_SCALE);
      for (int j = 0; j < 4; ++j) aq[kk][4 + j] = (_Float16)(q1[j] * INV_SCALE);
    }
  }

  f32x4 oacc[4] = {};
  float m[4], l[4];
  for (int r = 0; r < 4; ++r) { m[r] = -INFINITY; l[r] = 0.f; }

  for (int kt = 0; kt <= qt; ++kt) {
    __syncthreads();  // previous iteration's LDS reads done before overwrite

    // ---- stage K (row-major f16) and V (transposed f16); coalesced 16B/lane
    for (int i = 0; i < 4; ++i) {
      int f = i * 256 + tid;        // float4 index into the 64x64 tile
      int row = f >> 4;
      int col = (f & 15) << 2;
      const size_t g = base + (size_t)(kt * KVB + row) * D + col;
      f32x4 k4 = *(const f32x4*)(kp + g);
      f16x4 kh;
      for (int j = 0; j < 4; ++j) kh[j] = (_Float16)k4[j];
      *(f16x4*)&Kl[row][col] = kh;
      f32x4 v4 = *(const f32x4*)(vp + g);
      for (int j = 0; j < 4; ++j) Vt[col + j][row] = (_Float16)v4[j];
    }
    __syncthreads();

    const bool diag = (kt == qt);
    const int ctmax = diag ? wid : 3;  // skip fully-masked 16-col tiles

    // ---- S = (Q/8) K^T
    f32x4 sc[4];
    for (int ct = 0; ct <= ctmax; ++ct) {
      f16x8 b0 = *(const f16x8*)&Kl[ct * 16 + lq][lg * 8];
      f16x8 b1 = *(const f16x8*)&Kl[ct * 16 + lq][32 + lg * 8];
      f32x4 c = {};
      c = MFMA(aq[0], b0, c);
      c = MFMA(aq[1], b1, c);
      sc[ct] = c;
    }

    if (diag) {
      for (int ct = 0; ct <= ctmax; ++ct)
        for (int r = 0; r < 4; ++r) {
          int qrow = wid * 16 + lg * 4 + r;
          int kcol = ct * 16 + lq;
          if (kcol > qrow) sc[ct][r] = -INFINITY;
        }
    }

    // ---- row max: in-lane over ct, then across the 16 lanes sharing lg
    float rm[4];
    for (int r = 0; r < 4; ++r) {
      rm[r] = sc[0][r];
      for (int ct = 1; ct <= ctmax; ++ct) rm[r] = fmaxf(rm[r], sc[ct][r]);
    }
    for (int msk = 1; msk < 16; msk <<= 1)
      for (int r = 0; r < 4; ++r) rm[r] = fmaxf(rm[r], __shfl_xor(rm[r], msk));

    float alpha[4];
    for (int r = 0; r < 4; ++r) {
      float mn = fmaxf(m[r], rm[r]);
      alpha[r] = __expf(m[r] - mn);  // exp(-inf)=0 on first tile
      m[r] = mn;
    }

    // ---- P = exp(S - m), row sums
    float ps[4] = {0.f, 0.f, 0.f, 0.f};
    for (int ct = 0; ct <= ctmax; ++ct)
      for (int r = 0; r < 4; ++r) {
        float p = __expf(sc[ct][r] - m[r]);
        sc[ct][r] = p;
        ps[r] += p;
      }
    for (int msk = 1; msk < 16; msk <<= 1)
      for (int r = 0; r < 4; ++r) ps[r] += __shfl_xor(ps[r], msk);
    for (int r = 0; r < 4; ++r) l[r] = l[r] * alpha[r] + ps[r];

    for (int dt = 0; dt < 4; ++dt)
      for (int r = 0; r < 4; ++r) oacc[dt][r] *= alpha[r];

    // ---- P -> LDS (f16), zeroing masked-out column tiles
    for (int ct = 0; ct < 4; ++ct)
      for (int r = 0; r < 4; ++r)
        Pl[wid][lg * 4 + r][ct * 16 + lq] =
            (_Float16)(ct <= ctmax ? sc[ct][r] : 0.f);

    // ---- O += P V
    f16x8 pa0 = *(const f16x8*)&Pl[wid][lq][lg * 8];
    f16x8 pa1 = *(const f16x8*)&Pl[wid][lq][32 + lg * 8];
    for (int dt = 0; dt < 4; ++dt) {
      f16x8 v0 = *(const f16x8*)&Vt[dt * 16 + lq][lg * 8];
      f16x8 v1 = *(const f16x8*)&Vt[dt * 16 + lq][32 + lg * 8];
      oacc[dt] = MFMA(pa0, v0, oacc[dt]);
      oacc[dt] = MFMA(pa1, v1, oacc[dt]);
    }
  }

  // ---- epilogue: O / l
  for (int r = 0; r < 4; ++r) {
    float inv = 1.f / l[r];
    float* og = op + base + (size_t)(qt * QTILE + wid * 16 + lg * 4 + r) * D;
    for (int dt = 0; dt < 4; ++dt) og[dt * 16 + lq] = oacc[dt][r] * inv;
  }
}

extern "C" void kernel_launch(void* const* d_in, const int* in_sizes, int n_in,
                              void* d_out, int out_size, void* d_ws, size_t ws_size,
                              hipStream_t stream) {
  const float* q = (const float*)d_in[0];
  const float* k = (const float*)d_in[1];
  const float* v = (const float*)d_in[2];
  float* out = (float*)d_out;
  dim3 grid(NQT, BH);
  attn_fwd<<<grid, 256, 0, stream>>>(q, k, v, out);
}

// Round 2
// 245.540 us; speedup vs baseline: 1.4923x; 1.4923x over previous
//
#include <hip/hip_runtime.h>
#include <math.h>

constexpr int B = 4, H = 16, S = 2048, D = 64;
constexpr int BH = B * H;
constexpr int QTILE = 128;      // q rows per block (8 waves x 16)
constexpr int KVB = 64;         // kv rows per iteration
constexpr int NQT = S / QTILE;  // 16
constexpr float QSCALE = 0.18033688011112042f;  // log2(e)/8 : softmax in exp2 domain

typedef float f32x4 __attribute__((ext_vector_type(4)));
typedef _Float16 f16x8 __attribute__((ext_vector_type(8)));
typedef _Float16 f16x4 __attribute__((ext_vector_type(4)));

#define MFMA __builtin_amdgcn_mfma_f32_16x16x32_f16

#if __has_builtin(__builtin_amdgcn_exp2f)
#define EXP2(x) __builtin_amdgcn_exp2f(x)
#else
#define EXP2(x) exp2f(x)
#endif

// XOR swizzle: bank period 64 rows instead of 8 -> all phases <=2-way (free)
__device__ __forceinline__ int swzb(int row) { return ((row & 7) ^ (row >> 3)) << 3; }

// 8 waves, each owns 16 q rows. MFMA 16x16x32 f16.
// A-frag: row=lane&15, k=(lane>>4)*8+j. B-frag: col=lane&15, k=(lane>>4)*8+j.
// C/D: col=lane&15, row=(lane>>4)*4+reg  [m89/m91]
__global__ __launch_bounds__(512, 4)
void attn_fwd(const float* __restrict__ qp, const float* __restrict__ kp,
              const float* __restrict__ vp, float* __restrict__ op) {
  __shared__ _Float16 Kl[KVB * 64];      // Kl[k][d], swizzled rows
  __shared__ _Float16 Vt[64 * KVB];      // Vt[d][k], swizzled rows
  __shared__ _Float16 Pl[8 * 16 * 64];   // per-wave P tile, swizzled rows

  const int bh = blockIdx.x;
  // per-CU balance: resident groups share y&3; each row {g[k],g[k+4],g[k+8],g[k+12]} sums 30
  constexpr int g[16] = {15, 1, 11, 5, 0, 14, 4, 10, 13, 3, 9, 7, 2, 12, 6, 8};
  const int qt = g[blockIdx.y];

  const int tid = threadIdx.x;
  const int wid = tid >> 6;
  const int lane = tid & 63;
  const int lq = lane & 15;
  const int lg = lane >> 4;

  const size_t base = (size_t)bh * (S * D);
  const int R = qt * QTILE + wid * 16;  // wave's first q row

  // ---- Q fragments, pre-scaled by log2(e)/sqrt(D)
  f16x8 aq[2];
  {
    const float* qg = qp + base + (size_t)(R + lq) * D;
    for (int kk = 0; kk < 2; ++kk) {
      f32x4 q0 = *(const f32x4*)(qg + kk * 32 + lg * 8);
      f32x4 q1 = *(const f32x4*)(qg + kk * 32 + lg * 8 + 4);
      for (int j = 0; j < 4; ++j) aq[kk][j] = (_Float16)(q0[j] * QSCALE);
      for (int j = 0; j < 4; ++j) aq[kk][4 + j] = (_Float16)(q1[j] * QSCALE);
    }
  }

  f32x4 oacc[5] = {};  // [0..3] = O d-tiles, [4] = l accumulator (col 0 via ones-frag)
  float m[4];
  for (int r = 0; r < 4; ++r) m[r] = -INFINITY;

  // constant ones B-frag: B[k][0]=1 -> P*ones accumulates row sums into col 0
  f16x8 onesb;
  for (int j = 0; j < 8; ++j) onesb[j] = (lq == 0) ? (_Float16)1.0f : (_Float16)0.0f;

  const int ktmax = 2 * qt + 1;

  // staging geometry: 512 threads, 2 x float4 per thread per tensor
  const int srow = tid >> 4;          // 0..31 (+32 at i=1)
  const int scol = (tid & 15) << 2;   // 0,4,...,60

  // ---- prefetch tile 0 (T14: reg staging, latency hides under compute)
  f32x4 kpre[2], vpre[2];
  for (int i = 0; i < 2; ++i) {
    const size_t goff = base + (size_t)(i * 32 + srow) * D + scol;
    kpre[i] = *(const f32x4*)(kp + goff);
    vpre[i] = *(const f32x4*)(vp + goff);
  }

  for (int kt = 0; kt <= ktmax; ++kt) {
    __syncthreads();  // all waves done reading LDS tile kt-1

    // ---- write staged regs -> LDS (f16, swizzled)
    for (int i = 0; i < 2; ++i) {
      const int row = i * 32 + srow;
      f16x4 kh;
      for (int j = 0; j < 4; ++j) kh[j] = (_Float16)kpre[i][j];
      *(f16x4*)&Kl[(row << 6) + (swzb(row) ^ scol)] = kh;
      for (int j = 0; j < 4; ++j) {
        const int d = scol + j;
        Vt[(d << 6) + (swzb(d) ^ row)] = (_Float16)vpre[i][j];
      }
    }
    // ---- issue next tile's loads now; they complete during compute
    if (kt < ktmax) {
      const size_t nb = base + (size_t)((kt + 1) * KVB) * D;
      for (int i = 0; i < 2; ++i) {
        const size_t goff = nb + (size_t)(i * 32 + srow) * D + scol;
        kpre[i] = *(const f32x4*)(kp + goff);
        vpre[i] = *(const f32x4*)(vp + goff);
      }
    }
    __syncthreads();

    const int ck = kt * KVB;
    if (ck > R + 15) continue;  // wave fully masked; barriers already done

    const int rel15 = R + 15 - ck;
    const int ctmax = rel15 >= 63 ? 3 : (rel15 >> 4);
    const bool needmask = (ck + 63 > R);

    // ---- S = (Q * log2e/8) K^T
    f32x4 sc[4];
    for (int ct = 0; ct <= ctmax; ++ct) {
      const int row = ct * 16 + lq;
      const int sw = swzb(row);
      f16x8 b0 = *(const f16x8*)&Kl[(row << 6) + (sw ^ (lg * 8))];
      f16x8 b1 = *(const f16x8*)&Kl[(row << 6) + (sw ^ (32 + lg * 8))];
      f32x4 c = {};
      c = MFMA(aq[0], b0, c, 0, 0, 0);
      c = MFMA(aq[1], b1, c, 0, 0, 0);
      sc[ct] = c;
    }

    if (needmask) {
      const int rel = R - ck + lg * 4;  // mask col > row
      for (int ct = 0; ct <= ctmax; ++ct)
        for (int r = 0; r < 4; ++r)
          if (ct * 16 + lq > rel + r) sc[ct][r] = -INFINITY;
    }

    // ---- row max: in-lane over ct, then 16-lane butterfly on packed f16 pairs
    float rm0 = sc[0][0], rm1 = sc[0][1], rm2 = sc[0][2], rm3 = sc[0][3];
    for (int ct = 1; ct <= ctmax; ++ct) {
      rm0 = fmaxf(rm0, sc[ct][0]);
      rm1 = fmaxf(rm1, sc[ct][1]);
      rm2 = fmaxf(rm2, sc[ct][2]);
      rm3 = fmaxf(rm3, sc[ct][3]);
    }
    auto ha = __builtin_amdgcn_cvt_pkrtz(rm0, rm1);
    auto hb = __builtin_amdgcn_cvt_pkrtz(rm2, rm3);
    for (int msk = 1; msk < 16; msk <<= 1) {
      auto ta = __builtin_bit_cast(decltype(ha), __shfl_xor(__builtin_bit_cast(float, ha), msk));
      auto tb = __builtin_bit_cast(decltype(hb), __shfl_xor(__builtin_bit_cast(float, hb), msk));
      ha[0] = ha[0] > ta[0] ? ha[0] : ta[0];
      ha[1] = ha[1] > ta[1] ? ha[1] : ta[1];
      hb[0] = hb[0] > tb[0] ? hb[0] : tb[0];
      hb[1] = hb[1] > tb[1] ? hb[1] : tb[1];
    }
    const float nm[4] = {(float)ha[0], (float)ha[1], (float)hb[0], (float)hb[1]};

    float alpha[4];
    for (int r = 0; r < 4; ++r) {
      const float mn = fmaxf(m[r], nm[r]);
      alpha[r] = EXP2(m[r] - mn);  // exp2(-inf)=0 on first tile
      m[r] = mn;
    }

    // ---- P = exp2(S - m)
    for (int ct = 0; ct <= ctmax; ++ct)
      for (int r = 0; r < 4; ++r) sc[ct][r] = EXP2(sc[ct][r] - m[r]);

    // rescale O and l by alpha
    for (int t = 0; t < 5; ++t)
      for (int r = 0; r < 4; ++r) oacc[t][r] *= alpha[r];

    // ---- P -> LDS (f16, swizzled), zeroing skipped column tiles
    const int pbase = wid << 10;
    for (int r = 0; r < 4; ++r) {
      const int row = lg * 4 + r;
      const int rb = pbase + (row << 6);
      const int sw = swzb(row);
      for (int ct = 0; ct < 4; ++ct)
        Pl[rb + (sw ^ (ct * 16 + lq))] = (_Float16)(ct <= ctmax ? sc[ct][r] : 0.0f);
    }
    const int pb2 = pbase + (lq << 6);
    const int swq = swzb(lq);
    f16x8 pa0 = *(const f16x8*)&Pl[pb2 + (swq ^ (lg * 8))];
    f16x8 pa1 = *(const f16x8*)&Pl[pb2 + (swq ^ (32 + lg * 8))];

    // ---- O += P V ; l += P 1
    for (int dt = 0; dt < 4; ++dt) {
      const int row = dt * 16 + lq;
      const int sw = swzb(row);
      f16x8 v0 = *(const f16x8*)&Vt[(row << 6) + (sw ^ (lg * 8))];
      f16x8 v1 = *(const f16x8*)&Vt[(row << 6) + (sw ^ (32 + lg * 8))];
      oacc[dt] = MFMA(pa0, v0, oacc[dt], 0, 0, 0);
      oacc[dt] = MFMA(pa1, v1, oacc[dt], 0, 0, 0);
    }
    oacc[4] = MFMA(pa0, onesb, oacc[4], 0, 0, 0);
    oacc[4] = MFMA(pa1, onesb, oacc[4], 0, 0, 0);
  }

  // ---- epilogue: O / l  (l lives in col 0 of oacc[4] -> lanes with lq==0)
  for (int r = 0; r < 4; ++r) {
    const float l = __shfl(oacc[4][r], lane & 48);
    const float inv = 1.0f / l;
    float* og = op + base + (size_t)(R + lg * 4 + r) * D;
    for (int dt = 0; dt < 4; ++dt) og[dt * 16 + lq] = oacc[dt][r] * inv;
  }
}

extern "C" void kernel_launch(void* const* d_in, const int* in_sizes, int n_in,
                              void* d_out, int out_size, void* d_ws, size_t ws_size,
                              hipStream_t stream) {
  const float* q = (const float*)d_in[0];
  const float* k = (const float*)d_in[1];
  const float* v = (const float*)d_in[2];
  float* out = (float*)d_out;
  dim3 grid(BH, NQT);
  attn_fwd<<<grid, 512, 0, stream>>>(q, k, v, out);
}

// Round 4
// 126.668 us; speedup vs baseline: 2.8927x; 1.9385x over previous
//
#include <hip/hip_runtime.h>
#include <math.h>

constexpr int B = 4, H = 16, S = 2048, D = 64;
constexpr int BH = B * H;
constexpr int QTILE = 128;      // 8 waves x 16 q rows
constexpr int KVB = 64;
constexpr int NQT = S / QTILE;  // 16
constexpr float QSCALE = 0.18033688011112042f;  // log2(e)/8 : exp2-domain softmax
constexpr float DMTHR = 5.0f;   // defer-max threshold (exp2 domain, P <= 32)

typedef float f32x4 __attribute__((ext_vector_type(4)));
typedef _Float16 f16x8 __attribute__((ext_vector_type(8)));
typedef _Float16 f16x2 __attribute__((ext_vector_type(2)));

#define MFMA __builtin_amdgcn_mfma_f32_16x16x32_f16

#if __has_builtin(__builtin_amdgcn_exp2f)
#define EXP2(x) __builtin_amdgcn_exp2f(x)
#else
#define EXP2(x) exp2f(x)
#endif

#define PKRTZ(a, b) __builtin_bit_cast(f16x2, __builtin_amdgcn_cvt_pkrtz((a), (b)))

// XOR swizzle (units of 8 halves): bank period 64 rows -> near-conflict-free
__device__ __forceinline__ int swzb(int row) { return ((row & 7) ^ (row >> 3)) << 3; }
// V row permutation k -> p so PV A-frag is lane-local: p = pi(k), phi(p)=k
__device__ __forceinline__ int vperm(int k) {
  return (k & 32) | (((k >> 2) & 3) << 3) | (((k >> 4) & 1) << 2) | (k & 3);
}

// Swapped flash attention: S^T = mfma(K, Q) so each lane owns one q row's scores.
// A/B-frag: lane (lq,lg) holds [idx=lq][p=8lg+j].  C/D: [row=4lg+r][col=lq].
__global__ __launch_bounds__(512, 4)
void attn_fwd(const float* __restrict__ qp, const float* __restrict__ kp,
              const float* __restrict__ vp, float* __restrict__ op) {
  __shared__ _Float16 Kl[KVB * 64];   // Kl[k][d], swizzled
  __shared__ _Float16 Vtp[64 * KVB];  // Vtp[d][pi(k)], swizzled

  const int bh = blockIdx.x;
  // per-CU balance: resident quads y, y+4, y+8, y+12 each sum qt = 30
  constexpr int g[16] = {15, 1, 11, 5, 0, 14, 4, 10, 13, 3, 9, 7, 2, 12, 6, 8};
  const int qt = g[blockIdx.y];

  const int tid = threadIdx.x;
  const int wid = tid >> 6;
  const int lane = tid & 63;
  const int lq = lane & 15;
  const int lg = lane >> 4;

  const size_t base = (size_t)bh * (S * D);
  const int R = qt * QTILE + wid * 16;

  // ---- Q fragments (PV-side B operand), pre-scaled
  f16x8 aq[2];
  {
    const float* qg = qp + base + (size_t)(R + lq) * D;
    for (int kk = 0; kk < 2; ++kk) {
      f32x4 q0 = *(const f32x4*)(qg + kk * 32 + lg * 8);
      f32x4 q1 = *(const f32x4*)(qg + kk * 32 + lg * 8 + 4);
      for (int j = 0; j < 4; ++j) aq[kk][j] = (_Float16)(q0[j] * QSCALE);
      for (int j = 0; j < 4; ++j) aq[kk][4 + j] = (_Float16)(q1[j] * QSCALE);
    }
  }

  f32x4 oacc[4] = {};          // O[q=4lg+r][d=16dt+lq]
  float m = -INFINITY, l = 0.f;  // per-lane: q = R+lq

  const int ktmax = 2 * qt + 1;

  // staging: thread -> (row = tid>>3, 8-col group)
  const int srow = tid >> 3;
  const int sc8 = (tid & 7) << 3;
  const int kwaddr = (srow << 6) + (swzb(srow) ^ sc8);
  const int vpp = vperm(srow);

  f32x4 kr0, kr1, vr0, vr1;  // T14 reg prefetch
  {
    const float* kg = kp + base + (size_t)srow * D + sc8;
    const float* vg = vp + base + (size_t)srow * D + sc8;
    kr0 = *(const f32x4*)kg; kr1 = *(const f32x4*)(kg + 4);
    vr0 = *(const f32x4*)vg; vr1 = *(const f32x4*)(vg + 4);
  }

  for (int kt = 0; kt <= ktmax; ++kt) {
    __syncthreads();
    // ---- staged regs -> LDS
    {
      f16x8 kh;
      for (int j = 0; j < 4; ++j) kh[j] = (_Float16)kr0[j];
      for (int j = 0; j < 4; ++j) kh[4 + j] = (_Float16)kr1[j];
      *(f16x8*)&Kl[kwaddr] = kh;  // one b128, conflict-optimal
      for (int j = 0; j < 4; ++j) {
        const int d = sc8 + j;
        Vtp[(d << 6) + (swzb(d) ^ vpp)] = (_Float16)vr0[j];
      }
      for (int j = 0; j < 4; ++j) {
        const int d = sc8 + 4 + j;
        Vtp[(d << 6) + (swzb(d) ^ vpp)] = (_Float16)vr1[j];
      }
    }
    // ---- issue next tile's loads; complete during compute
    if (kt < ktmax) {
      const float* kg = kp + base + (size_t)((kt + 1) * KVB + srow) * D + sc8;
      const float* vg = vp + base + (size_t)((kt + 1) * KVB + srow) * D + sc8;
      kr0 = *(const f32x4*)kg; kr1 = *(const f32x4*)(kg + 4);
      vr0 = *(const f32x4*)vg; vr1 = *(const f32x4*)(vg + 4);
    }
    __syncthreads();

    const int ck = kt * KVB;
    if (ck > R + 15) continue;  // fully masked for this wave
    const int rel15 = R + 15 - ck;
    const int ctmax = rel15 >= 63 ? 3 : (rel15 >> 4);
    const bool needmask = (ck + 63 > R);

    // ---- S^T = mfma(K, Q): lane holds S[q=R+lq][k=ck+16ct+4lg+r]
    f32x4 sc4[4];
    for (int ct = 0; ct < 4; ++ct) {
      if (ct > ctmax) continue;
      const int row = ct * 16 + lq;
      const int sw = swzb(row);
      f16x8 a0 = *(const f16x8*)&Kl[(row << 6) + (sw ^ (lg * 8))];
      f16x8 a1 = *(const f16x8*)&Kl[(row << 6) + (sw ^ (32 + lg * 8))];
      f32x4 c = {};
      c = MFMA(a0, aq[0], c, 0, 0, 0);
      c = MFMA(a1, aq[1], c, 0, 0, 0);
      sc4[ct] = c;
    }

    if (needmask) {
      const int qrel = R - ck + lq;  // mask k > q
      for (int ct = 0; ct <= ctmax; ++ct)
        for (int r = 0; r < 4; ++r)
          if (ct * 16 + lg * 4 + r > qrel) sc4[ct][r] = -INFINITY;
    }

    // ---- row max: in-lane + 2 shuffles
    float pmax = sc4[0][0];
    for (int ct = 0; ct <= ctmax; ++ct)
      for (int r = 0; r < 4; ++r) pmax = fmaxf(pmax, sc4[ct][r]);
    pmax = fmaxf(pmax, __shfl_xor(pmax, 16));
    pmax = fmaxf(pmax, __shfl_xor(pmax, 32));

    // ---- defer-max (T13): rescale only when the max really grew
    if (!__all(pmax - m <= DMTHR)) {
      const float mn = fmaxf(m, pmax);
      const float alpha = EXP2(m - mn);  // 0 on first tile
      m = mn;
      l *= alpha;
      float ar[4];
      for (int r = 0; r < 4; ++r) ar[r] = __shfl(alpha, 20 * lg + r);
      for (int dt = 0; dt < 4; ++dt)
        for (int r = 0; r < 4; ++r) oacc[dt][r] *= ar[r];
    }

    // ---- P = exp2(S - m); per-lane partial row sum
    float ps = 0.f;
    for (int ct = 0; ct <= ctmax; ++ct)
      for (int r = 0; r < 4; ++r) {
        const float p = EXP2(sc4[ct][r] - m);
        sc4[ct][r] = p;
        ps += p;
      }
    l += ps;
    for (int ct = ctmax + 1; ct < 4; ++ct) sc4[ct] = (f32x4){0.f, 0.f, 0.f, 0.f};

    // ---- pack P into PV A-frags (pure in-lane, phi-mapping)
    f16x8 pa0, pa1;
    {
      f16x2 t;
      t = PKRTZ(sc4[0][0], sc4[0][1]); pa0[0] = t[0]; pa0[1] = t[1];
      t = PKRTZ(sc4[0][2], sc4[0][3]); pa0[2] = t[0]; pa0[3] = t[1];
      t = PKRTZ(sc4[1][0], sc4[1][1]); pa0[4] = t[0]; pa0[5] = t[1];
      t = PKRTZ(sc4[1][2], sc4[1][3]); pa0[6] = t[0]; pa0[7] = t[1];
      t = PKRTZ(sc4[2][0], sc4[2][1]); pa1[0] = t[0]; pa1[1] = t[1];
      t = PKRTZ(sc4[2][2], sc4[2][3]); pa1[2] = t[0]; pa1[3] = t[1];
      t = PKRTZ(sc4[3][0], sc4[3][1]); pa1[4] = t[0]; pa1[5] = t[1];
      t = PKRTZ(sc4[3][2], sc4[3][3]); pa1[6] = t[0]; pa1[7] = t[1];
    }

    // ---- O += P V  (B-frags from permuted Vtp, single b128 each)
    for (int dt = 0; dt < 4; ++dt) {
      const int row = dt * 16 + lq;
      const int sw = swzb(row);
      f16x8 v0 = *(const f16x8*)&Vtp[(row << 6) + (sw ^ (lg * 8))];
      oacc[dt] = MFMA(pa0, v0, oacc[dt], 0, 0, 0);
    }
    if (ctmax >= 2) {
      for (int dt = 0; dt < 4; ++dt) {
        const int row = dt * 16 + lq;
        const int sw = swzb(row);
        f16x8 v1 = *(const f16x8*)&Vtp[(row << 6) + (sw ^ (32 + lg * 8))];
        oacc[dt] = MFMA(pa1, v1, oacc[dt], 0, 0, 0);
      }
    }
  }

  // ---- epilogue: combine l across lg, redistribute, write O/l
  float lt = l + __shfl_xor(l, 16);
  lt += __shfl_xor(lt, 32);
  const float inv = 1.f / lt;
  float ar[4];
  for (int r = 0; r < 4; ++r) ar[r] = __shfl(inv, 20 * lg + r);
  for (int r = 0; r < 4; ++r) {
    float* og = op + base + (size_t)(R + lg * 4 + r) * D;
    for (int dt = 0; dt < 4; ++dt) og[dt * 16 + lq] = oacc[dt][r] * ar[r];
  }
}

extern "C" void kernel_launch(void* const* d_in, const int* in_sizes, int n_in,
                              void* d_out, int out_size, void* d_ws, size_t ws_size,
                              hipStream_t stream) {
  const float* q = (const float*)d_in[0];
  const float* k = (const float*)d_in[1];
  const float* v = (const float*)d_in[2];
  float* out = (float*)d_out;
  dim3 grid(BH, NQT);
  attn_fwd<<<grid, 512, 0, stream>>>(q, k, v, out);
}

// Round 6
// 101.479 us; speedup vs baseline: 3.6107x; 1.2482x over previous
//
#include <hip/hip_runtime.h>
#include <math.h>

constexpr int S = 2048, D = 64;
constexpr int BH = 64;
constexpr int QTILE = 256;      // 8 waves x 32 q rows
constexpr int KVB = 64;
constexpr int NQT = S / QTILE;  // 8
constexpr float QSCALE = 0.18033688011112042f;  // log2(e)/8
constexpr float DMTHR = 5.0f;   // defer-max threshold (exp2 domain)

typedef float f32x4 __attribute__((ext_vector_type(4)));
typedef float f32x16 __attribute__((ext_vector_type(16)));
typedef _Float16 f16x8 __attribute__((ext_vector_type(8)));
typedef _Float16 f16x4 __attribute__((ext_vector_type(4)));
typedef unsigned int u32;
typedef unsigned int u32x4 __attribute__((ext_vector_type(4)));

#define MFMA32(a, b, c) __builtin_amdgcn_mfma_f32_32x32x16_f16((a), (b), (c), 0, 0, 0)

#if __has_builtin(__builtin_amdgcn_exp2f)
#define EXP2(x) __builtin_amdgcn_exp2f(x)
#else
#define EXP2(x) exp2f(x)
#endif

__device__ __forceinline__ u32 pkbits(float a, float b) {
  return __builtin_bit_cast(u32, __builtin_amdgcn_cvt_pkrtz(a, b));
}
// a' = {a.lo31, b.lo31}, b' = {a.hi31, b.hi31} (swap a's upper half w/ b's lower)
__device__ __forceinline__ void plswap(u32& a, u32& b) {
  asm volatile("v_permlane32_swap_b32 %0, %1" : "+v"(a), "+v"(b));
}
// XOR swizzle (units of 8 halves): bank period 64 rows
__device__ __forceinline__ int swzb(int row) { return ((row & 7) ^ (row >> 3)) << 3; }

// 32x32x16 swapped flash attn. A-frag: row=l&31, k=(l>>5)*8+j. B-frag: col=l&31 (q).
// C/D: col=l&31 (q), row=(reg&3)+8*(reg>>2)+4*(l>>5)  [m74/m101]
__global__ __launch_bounds__(512, 4)
void attn_fwd(const float* __restrict__ qp, const float* __restrict__ kp,
              const float* __restrict__ vp, float* __restrict__ op) {
  __shared__ _Float16 Kl[2][KVB * 64];  // Kl[buf][k][d], swizzled rows
  __shared__ _Float16 Vt[2][64 * KVB];  // Vt[buf][d][k], swizzled rows

  const int bh = blockIdx.x;
  constexpr int g8[8] = {7, 6, 5, 4, 0, 1, 2, 3};  // CU pairs (y, y+4) sum 7
  const int qt = g8[blockIdx.y];

  const int tid = threadIdx.x;
  const int wid = tid >> 6;
  const int lane = tid & 63;
  const int q32 = lane & 31;
  const int hi = lane >> 5;

  const size_t base = (size_t)bh * (S * D);
  const int Rp = qt * QTILE + wid * 32;  // wave's first q row

  // ---- Q B-frags: bq[t][j] = Q[Rp+q32][16t + 8hi + j] * QSCALE
  f16x8 bq[4];
  {
    const float* qg = qp + base + (size_t)(Rp + q32) * D + 8 * hi;
#pragma unroll
    for (int t = 0; t < 4; ++t) {
      f32x4 a = *(const f32x4*)(qg + 16 * t);
      f32x4 b = *(const f32x4*)(qg + 16 * t + 4);
#pragma unroll
      for (int j = 0; j < 4; ++j) bq[t][j] = (_Float16)(a[j] * QSCALE);
#pragma unroll
      for (int j = 0; j < 4; ++j) bq[t][4 + j] = (_Float16)(b[j] * QSCALE);
    }
  }

  f32x16 od0 = {}, od1 = {};      // O^T: d = 32*dt + 8*(r>>2) + 4*hi + (r&3), q = q32
  float m = -INFINITY, l = 0.f;   // per-lane, own q row

  const int ktmax = 4 * qt + 3;

  // ---- staging: row-pair rp, 4-col group cg
  const int rp = tid >> 4;        // 0..31
  const int cg = tid & 15;
  const int r0 = 2 * rp, r1 = 2 * rp + 1;
  const int c4 = cg * 4;
  const int kw0 = (r0 << 6) + (swzb(r0) ^ c4);
  const int kw1 = (r1 << 6) + (swzb(r1) ^ c4);
  int vw[4];
#pragma unroll
  for (int j = 0; j < 4; ++j) { const int d = c4 + j; vw[j] = (d << 6) + (swzb(d) ^ r0); }

  f32x4 kr0, kr1, vr0, vr1;  // T14 reg prefetch
  {
    const float* kg = kp + base + (size_t)r0 * D + c4;
    const float* vg = vp + base + (size_t)r0 * D + c4;
    kr0 = *(const f32x4*)kg; kr1 = *(const f32x4*)(kg + D);
    vr0 = *(const f32x4*)vg; vr1 = *(const f32x4*)(vg + D);
  }

  for (int kt = 0; kt <= ktmax; ++kt) {
    const int bufp = kt & 1;
    // ---- staged regs -> LDS (f16): K 2x b64, V 4x pk'd b32 (2-way free)
    {
      f16x4 k0h, k1h;
#pragma unroll
      for (int j = 0; j < 4; ++j) { k0h[j] = (_Float16)kr0[j]; k1h[j] = (_Float16)kr1[j]; }
      *(f16x4*)&Kl[bufp][kw0] = k0h;
      *(f16x4*)&Kl[bufp][kw1] = k1h;
#pragma unroll
      for (int j = 0; j < 4; ++j) *(u32*)&Vt[bufp][vw[j]] = pkbits(vr0[j], vr1[j]);
    }
    // ---- issue next tile's loads; land during compute
    if (kt < ktmax) {
      const float* kg = kp + base + (size_t)((kt + 1) * KVB + r0) * D + c4;
      const float* vg = vp + base + (size_t)((kt + 1) * KVB + r0) * D + c4;
      kr0 = *(const f32x4*)kg; kr1 = *(const f32x4*)(kg + D);
      vr0 = *(const f32x4*)vg; vr1 = *(const f32x4*)(vg + D);
    }
    __syncthreads();  // buf[bufp] ready; single barrier/iter (dbuf induction)

    const int ck = kt * KVB;
    if (ck > Rp + 31) continue;       // wave fully masked
    const int rel = Rp - ck;          // >= 0, multiple of 32
    const int ctmax = (rel >= 32) ? 1 : 0;
    const bool needmask = (32 * ctmax + 31 > rel);

    const _Float16* Kb = Kl[bufp];
    const _Float16* Vb = Vt[bufp];

    // ---- S^T = mfma(K, Q): lane owns q=Rp+q32, k = 32ct + 8*(r>>2)+4hi+(r&3)
    f32x16 st0 = {}, st1 = {};
    __builtin_amdgcn_s_setprio(1);
#pragma unroll
    for (int t = 0; t < 4; ++t) {
      f16x8 a = *(const f16x8*)&Kb[(q32 << 6) + (swzb(q32) ^ (16 * t + 8 * hi))];
      st0 = MFMA32(a, bq[t], st0);
    }
    if (ctmax) {
      const int row = 32 + q32;
#pragma unroll
      for (int t = 0; t < 4; ++t) {
        f16x8 a = *(const f16x8*)&Kb[(row << 6) + (swzb(row) ^ (16 * t + 8 * hi))];
        st1 = MFMA32(a, bq[t], st1);
      }
    }
    __builtin_amdgcn_s_setprio(0);

    if (needmask) {  // one diagonal tile per wave over whole kernel
      const int qrel = rel + q32;
#pragma unroll
      for (int gq = 0; gq < 4; ++gq)
#pragma unroll
        for (int i = 0; i < 4; ++i) {
          if (8 * gq + 4 * hi + i > qrel) st0[4 * gq + i] = -INFINITY;
          if (ctmax && (32 + 8 * gq + 4 * hi + i > qrel)) st1[4 * gq + i] = -INFINITY;
        }
    }

    // ---- row max: in-lane + 1 shuffle (partner l^32 has same q)
    float pmax = st0[0];
#pragma unroll
    for (int r = 1; r < 16; ++r) pmax = fmaxf(pmax, st0[r]);
    if (ctmax)
#pragma unroll
      for (int r = 0; r < 16; ++r) pmax = fmaxf(pmax, st1[r]);
    pmax = fmaxf(pmax, __shfl_xor(pmax, 32));

    // ---- defer-max (T13): rescale is pure per-lane (no redistribution!)
    if (!__all(pmax - m <= DMTHR)) {
      const float mn = fmaxf(m, pmax);
      const float alpha = EXP2(m - mn);
      m = mn;
      l *= alpha;
#pragma unroll
      for (int r = 0; r < 16; ++r) od0[r] *= alpha;
#pragma unroll
      for (int r = 0; r < 16; ++r) od1[r] *= alpha;
    }

    // ---- P = exp2(S - m); in-lane partial sum
    float ps = 0.f;
#pragma unroll
    for (int r = 0; r < 16; ++r) { const float p = EXP2(st0[r] - m); st0[r] = p; ps += p; }
    if (ctmax)
#pragma unroll
      for (int r = 0; r < 16; ++r) { const float p = EXP2(st1[r] - m); st1[r] = p; ps += p; }
    l += ps;

    // ---- P -> B-frag via cvt_pk + permlane32_swap (T12); O^T += mfma(V^T, P^T)
    __builtin_amdgcn_s_setprio(1);
#define PV_CT(stv, CT)                                                          \
    _Pragma("unroll")                                                           \
    for (int t = 0; t < 2; ++t) {                                               \
      u32 x0 = pkbits(stv[8 * t + 0], stv[8 * t + 1]);                          \
      u32 x1 = pkbits(stv[8 * t + 2], stv[8 * t + 3]);                          \
      u32 y0 = pkbits(stv[8 * t + 4], stv[8 * t + 5]);                          \
      u32 y1 = pkbits(stv[8 * t + 6], stv[8 * t + 7]);                          \
      plswap(x0, y0); plswap(x1, y1);                                           \
      const f16x8 pf = __builtin_bit_cast(f16x8, (u32x4){x0, x1, y0, y1});      \
      const int kcol = (2 * (CT) + t) * 16 + 8 * hi;                            \
      { const f16x8 vf = *(const f16x8*)&Vb[(q32 << 6) + (swzb(q32) ^ kcol)];   \
        od0 = MFMA32(vf, pf, od0); }                                            \
      { const int row = 32 + q32;                                               \
        const f16x8 vf = *(const f16x8*)&Vb[(row << 6) + (swzb(row) ^ kcol)];   \
        od1 = MFMA32(vf, pf, od1); }                                            \
    }
    PV_CT(st0, 0);
    if (ctmax) { PV_CT(st1, 1); }
#undef PV_CT
    __builtin_amdgcn_s_setprio(0);
  }

  // ---- epilogue: l across partner, scale, b128 stores
  const float lt = l + __shfl_xor(l, 32);
  const float inv = 1.f / lt;
  float* og = op + base + (size_t)(Rp + q32) * D + 4 * hi;
#pragma unroll
  for (int gq = 0; gq < 4; ++gq) {
    f32x4 w0, w1;
#pragma unroll
    for (int i = 0; i < 4; ++i) w0[i] = od0[4 * gq + i] * inv;
#pragma unroll
    for (int i = 0; i < 4; ++i) w1[i] = od1[4 * gq + i] * inv;
    *(f32x4*)(og + 8 * gq) = w0;
    *(f32x4*)(og + 32 + 8 * gq) = w1;
  }
}

extern "C" void kernel_launch(void* const* d_in, const int* in_sizes, int n_in,
                              void* d_out, int out_size, void* d_ws, size_t ws_size,
                              hipStream_t stream) {
  const float* q = (const float*)d_in[0];
  const float* k = (const float*)d_in[1];
  const float* v = (const float*)d_in[2];
  float* out = (float*)d_out;
  dim3 grid(BH, NQT);
  attn_fwd<<<grid, 512, 0, stream>>>(q, k, v, out);
}